// Round 12
// baseline (685.136 us; speedup 1.0000x reference)
//
#include <hip/hip_runtime.h>
#include <hip/hip_bf16.h>

// MindSpeedTEGroupedLinear: 64 experts, x[32768,2048]f32 @ W[e][1408,2048]^T f32
// R12 = R11 phase-split with the three defects fixed:
//  (1) raw s_barrier on P1-P3 (no lgkm drain; per-wave waits via C++ dataflow)
//  (2) ds_writes distributed into P2/P3/P4 between MFMA clusters
//  (3) t+2 loads issued P3/P4 -> multi-phase vmcnt cover; one drain-bar (P4).
#define E_ 64
#define K_ 2048
#define N_ 1408
#define BM 256
#define BN 128
#define BK 64
#define NT (K_ / BK)              // 32 K-tiles
#define NTHREADS 512
#define NTILE (N_ / BN)           // 11
#define LDSA_B (BM * BK * 2)      // 32768 B
#define LDSB_B (BN * BK * 2)      // 16384 B
#define LDSBUF (LDSA_B + LDSB_B)  // 49152 B
#define GRID_ 2112                // >= max J = 192*11; divisible by 8

using f32x4  = __attribute__((ext_vector_type(4))) float;
using bf16x8 = __attribute__((ext_vector_type(8))) short;

#define RAWBAR()   asm volatile("s_barrier" ::: "memory")
#define DRAINBAR() asm volatile("s_waitcnt lgkmcnt(0)\n\ts_barrier" ::: "memory")

__device__ __forceinline__ short f2b(float f) {
  __hip_bfloat16 h = __float2bfloat16(f);
  return __builtin_bit_cast(short, h);
}

// meta[0] = J; meta[1+e] = prefix of per-expert M-tile counts; meta[66+e] = row
// offset of expert e. One wave, ~2 us.
__global__ void build_meta(const int* __restrict__ m_splits, int* __restrict__ meta) {
  const int e = threadIdx.x;           // 0..63
  const int m = m_splits[e];
  const int mt = (m + BM - 1) / BM;
  int sm = m, smt = mt;
#pragma unroll
  for (int d = 1; d < 64; d <<= 1) {   // inclusive wave scan
    const int vm = __shfl_up(sm, d);
    const int vt = __shfl_up(smt, d);
    if (e >= d) { sm += vm; smt += vt; }
  }
  meta[1 + e] = smt - mt;              // exclusive prefix
  meta[66 + e] = sm - m;
  if (e == 63) { meta[1 + 64] = smt; meta[0] = smt * NTILE; }
}

__global__ __launch_bounds__(NTHREADS, 2) void gemm_grouped(
    const float* __restrict__ x, const float* __restrict__ W,
    const int* __restrict__ m_splits, const int* __restrict__ meta,
    float* __restrict__ out) {
  __shared__ char smem[2 * LDSBUF];   // 96 KiB -> 1 block/CU

  // Arithmetic job mapping; contiguous jidx chunks per XCD (bid%8 heuristic).
  const int J = meta[0];
  const int xcd = blockIdx.x & 7;
  const int pos = blockIdx.x >> 3;
  const int q = J >> 3, r = J & 7;
  if (pos >= q + (xcd < r ? 1 : 0)) return;           // padding block
  const int jidx = xcd * q + min(xcd, r) + pos;

  int lo = 0, hi = 64;                 // largest e with jb[e]*11 <= jidx
  while (hi - lo > 1) {
    const int mid = (lo + hi) >> 1;
    if (meta[1 + mid] * NTILE <= jidx) lo = mid; else hi = mid;
  }
  const int e = lo;
  const int mt_e = meta[1 + e + 1] - meta[1 + e];
  const int rem = jidx - meta[1 + e] * NTILE;
  const int nt = rem / mt_e;
  const int t_  = rem - nt * mt_e;
  const int m_e = m_splits[e];
  const int row0 = meta[66 + e] + t_ * BM;
  const int nrows = min(BM, m_e - t_ * BM);
  const int n0 = nt * BN;

  const int tid  = threadIdx.x;
  const int lane = tid & 63;
  const int w    = tid >> 6;   // 8 waves
  const int wm   = w >> 1;     // 0..3 (64-row stripe of 256)
  const int wn   = w & 1;      // 0..1 (64-col stripe of 128)

  // staging: A row covered by 2 threads (32 floats); B row by 4 (16 floats).
  const int arow_s = tid >> 1;            // 0..255
  const int acol_s = (tid & 1) * 32;
  const int brow_s = tid >> 2;            // 0..127
  const int bcol_s = (tid & 3) * 16;

  const float* xrow = x + (size_t)row0 * K_;
  const float* wrow = W + ((size_t)e * N_ + (size_t)n0) * K_;
  const f32x4 zero4 = {0.f, 0.f, 0.f, 0.f};

  f32x4 sa[8], sb[4];

  auto load_B = [&](int kt) {
    const float* p = wrow + (size_t)brow_s * K_ + kt * BK + bcol_s;
#pragma unroll
    for (int c = 0; c < 4; ++c) sb[c] = *(const f32x4*)(p + c * 4);
  };
  auto load_A0 = [&](int kt) {           // sa[0..3]
    if (arow_s < nrows) {
      const float* p = xrow + (size_t)arow_s * K_ + kt * BK + acol_s;
#pragma unroll
      for (int c = 0; c < 4; ++c) sa[c] = *(const f32x4*)(p + c * 4);
    } else {
#pragma unroll
      for (int c = 0; c < 4; ++c) sa[c] = zero4;
    }
  };
  auto load_A1 = [&](int kt) {           // sa[4..7]
    if (arow_s < nrows) {
      const float* p = xrow + (size_t)arow_s * K_ + kt * BK + acol_s + 16;
#pragma unroll
      for (int c = 0; c < 4; ++c) sa[4 + c] = *(const f32x4*)(p + c * 4);
    } else {
#pragma unroll
      for (int c = 0; c < 4; ++c) sa[4 + c] = zero4;
    }
  };

  // 128 B rows, 8x16B slots; slot ^= row&7 -> conflict-free frag access
  auto wrA2 = [&](int buf, int half) {   // half 0: chunks 0,1 (sa[0..3]); 1: 2,3
    const int ab = buf * LDSBUF;
#pragma unroll
    for (int cc = 0; cc < 2; ++cc) {
      const int c = half * 2 + cc;
      const int slot = ((tid & 1) * 4 + c) ^ (arow_s & 7);
      bf16x8 v;
#pragma unroll
      for (int i = 0; i < 4; ++i) { v[i] = f2b(sa[2 * c][i]); v[i + 4] = f2b(sa[2 * c + 1][i]); }
      *(bf16x8*)(smem + ab + arow_s * 128 + slot * 16) = v;
    }
  };
  auto wrB2 = [&](int buf) {
    const int ab = buf * LDSBUF;
#pragma unroll
    for (int c = 0; c < 2; ++c) {
      const int slot = ((tid & 3) * 2 + c) ^ (brow_s & 7);
      bf16x8 v;
#pragma unroll
      for (int i = 0; i < 4; ++i) { v[i] = f2b(sb[2 * c][i]); v[i + 4] = f2b(sb[2 * c + 1][i]); }
      *(bf16x8*)(smem + ab + LDSB_B * 0 + LDSA_B + brow_s * 128 + slot * 16) = v;
    }
  };

  const int arow0 = wm * 64 + (lane & 15);
  const int brow0 = wn * 64 + (lane & 15);
  const int kgrp  = lane >> 4;           // 0..3

  auto rdA = [&](int buf, int kk, int i) -> bf16x8 {
    const int row = arow0 + i * 16;
    const int slot = (kk * 4 + kgrp) ^ (row & 7);
    return *(const bf16x8*)(smem + buf * LDSBUF + row * 128 + slot * 16);
  };
  auto rdB = [&](int buf, int kk, int j) -> bf16x8 {
    const int row = brow0 + j * 16;
    const int slot = (kk * 4 + kgrp) ^ (row & 7);
    return *(const bf16x8*)(smem + buf * LDSBUF + LDSA_B + row * 128 + slot * 16);
  };

  f32x4 acc[4][4];
#pragma unroll
  for (int i = 0; i < 4; ++i)
#pragma unroll
    for (int j = 0; j < 4; ++j) acc[i][j] = zero4;

#define MFMA8(J0, J1)                                                         \
  __builtin_amdgcn_s_setprio(1);                                              \
  acc[0][J0] = __builtin_amdgcn_mfma_f32_16x16x32_bf16(fa0, fb0, acc[0][J0], 0, 0, 0); \
  acc[1][J0] = __builtin_amdgcn_mfma_f32_16x16x32_bf16(fa1, fb0, acc[1][J0], 0, 0, 0); \
  acc[2][J0] = __builtin_amdgcn_mfma_f32_16x16x32_bf16(fa2, fb0, acc[2][J0], 0, 0, 0); \
  acc[3][J0] = __builtin_amdgcn_mfma_f32_16x16x32_bf16(fa3, fb0, acc[3][J0], 0, 0, 0); \
  acc[0][J1] = __builtin_amdgcn_mfma_f32_16x16x32_bf16(fa0, fb1, acc[0][J1], 0, 0, 0); \
  acc[1][J1] = __builtin_amdgcn_mfma_f32_16x16x32_bf16(fa1, fb1, acc[1][J1], 0, 0, 0); \
  acc[2][J1] = __builtin_amdgcn_mfma_f32_16x16x32_bf16(fa2, fb1, acc[2][J1], 0, 0, 0); \
  acc[3][J1] = __builtin_amdgcn_mfma_f32_16x16x32_bf16(fa3, fb1, acc[3][J1], 0, 0, 0); \
  __builtin_amdgcn_s_setprio(0);

  // prologue: stage tile0 into buf0 (one exposed drain), preload tile1 into S
  load_B(0); load_A0(0); load_A1(0);
  wrA2(0, 0); wrA2(0, 1); wrB2(0);
  load_B(1); load_A0(1); load_A1(1);
  DRAINBAR();                            // publish buf0

  int cur = 0;
  for (int t = 0; t < NT; ++t) {
    const bool hn = (t + 1 < NT);
    const bool hn2 = (t + 2 < NT);
    const int nxt = cur ^ 1;
    bf16x8 fa0, fa1, fa2, fa3, fb0, fb1;
    // P1: reads only (writes unsafe until P1-bar proves prior reads consumed)
    fa0 = rdA(cur, 0, 0); fa1 = rdA(cur, 0, 1); fa2 = rdA(cur, 0, 2); fa3 = rdA(cur, 0, 3);
    fb0 = rdB(cur, 0, 0); fb1 = rdB(cur, 0, 1);
    RAWBAR();
    MFMA8(0, 1)
    // P2: 2 B-frag reads; write A-half0 of t+1 (S loaded >=4 phases ago)
    fb0 = rdB(cur, 0, 2); fb1 = rdB(cur, 0, 3);
    if (hn) wrA2(nxt, 0);
    RAWBAR();
    MFMA8(2, 3)
    // P3: kk=1 reads; write A-half1; issue A0 loads for t+2 (sa[0..3] free)
    fa0 = rdA(cur, 1, 0); fa1 = rdA(cur, 1, 1); fa2 = rdA(cur, 1, 2); fa3 = rdA(cur, 1, 3);
    fb0 = rdB(cur, 1, 0); fb1 = rdB(cur, 1, 1);
    if (hn) wrA2(nxt, 1);
    if (hn2) load_A0(t + 2);
    RAWBAR();
    MFMA8(0, 1)
    // P4: last reads; write B; issue remaining t+2 loads; drain publishes nxt
    fb0 = rdB(cur, 1, 2); fb1 = rdB(cur, 1, 3);
    if (hn) wrB2(nxt);
    if (hn2) { load_B(t + 2); load_A1(t + 2); }
    DRAINBAR();
    MFMA8(2, 3)
    cur = nxt;
  }
#undef MFMA8

  // epilogue: C/D layout col=lane&15, row=(lane>>4)*4+reg
  const int crow = wm * 64 + (lane >> 4) * 4;
  const int ccol = n0 + wn * 64 + (lane & 15);
#pragma unroll
  for (int i = 0; i < 4; ++i) {
#pragma unroll
    for (int rr = 0; rr < 4; ++rr) {
      const int lr = crow + i * 16 + rr;
      if (lr < nrows) {
#pragma unroll
        for (int j = 0; j < 4; ++j)
          out[(size_t)(row0 + lr) * N_ + ccol + j * 16] = acc[i][j][rr];
      }
    }
  }
}

extern "C" void kernel_launch(void* const* d_in, const int* in_sizes, int n_in,
                              void* d_out, int out_size, void* d_ws, size_t ws_size,
                              hipStream_t stream) {
  const float* x        = (const float*)d_in[0];
  const float* W        = (const float*)d_in[1];
  const int*   m_splits = (const int*)d_in[2];
  float*       out      = (float*)d_out;

  int* meta = (int*)d_ws;   // 131 ints

  build_meta<<<1, 64, 0, stream>>>(m_splits, meta);
  gemm_grouped<<<GRID_, NTHREADS, 0, stream>>>(x, W, m_splits, meta, out);
}

// Round 13
// 382.127 us; speedup vs baseline: 1.7930x; 1.7930x over previous
//
#include <hip/hip_runtime.h>
#include <hip/hip_bf16.h>

// MindSpeedTEGroupedLinear: 64 experts, x[32768,2048]f32 @ W[e][1408,2048]^T f32
// R13 = exact revert to R5 (measured champion, 431 us dispatch / 388 us wall).
// R5 is a sharp local optimum: 256x128 tile, BK=32, 1-deep reg prefetch,
// double-buffered 48 KiB LDS, lgkm-only barriers, VGPR 64+64acc = exactly the
// 128-reg occupancy boundary (2 blocks/CU). All 7 structural variants tried
// (write-early, 2-deep, setprio, 128^2 high-occ, phase-split x2) regressed.
#define E_ 64
#define K_ 2048
#define N_ 1408
#define BM 256
#define BN 128
#define BK 32
#define NK (K_ / BK)              // 64
#define NTHREADS 512
#define NTILE (N_ / BN)           // 11
#define LDSA (BM * BK * 2)        // 16384 B
#define LDSB (BN * BK * 2)        // 8192 B
#define LDSBUF (LDSA + LDSB)      // 24576 B
#define GRID_ 2112                // >= max J = (128+64)*11; divisible by 8

using f32x4  = __attribute__((ext_vector_type(4))) float;
using bf16x8 = __attribute__((ext_vector_type(8))) short;

// Drain LDS ops only; global loads stay in flight across the barrier.
#define BAR() asm volatile("s_waitcnt lgkmcnt(0)\n\ts_barrier" ::: "memory")

__device__ __forceinline__ short f2b(float f) {
  __hip_bfloat16 h = __float2bfloat16(f);
  return __builtin_bit_cast(short, h);
}

// meta[0] = J (total jobs); meta[1+e] = jb[e] (prefix of per-expert M-tile
// counts, e=0..64); meta[66+e] = row offset of expert e. One wave, ~2 us.
__global__ void build_meta(const int* __restrict__ m_splits, int* __restrict__ meta) {
  const int e = threadIdx.x;           // 0..63
  const int m = m_splits[e];
  const int mt = (m + BM - 1) / BM;
  int sm = m, smt = mt;
#pragma unroll
  for (int d = 1; d < 64; d <<= 1) {   // inclusive wave scan
    const int vm = __shfl_up(sm, d);
    const int vt = __shfl_up(smt, d);
    if (e >= d) { sm += vm; smt += vt; }
  }
  meta[1 + e] = smt - mt;              // exclusive prefix
  meta[66 + e] = sm - m;
  if (e == 63) { meta[1 + 64] = smt; meta[0] = smt * NTILE; }
}

struct Stage { f32x4 a[2][2]; f32x4 b[2]; };

__global__ __launch_bounds__(NTHREADS, 2) void gemm_grouped(
    const float* __restrict__ x, const float* __restrict__ W,
    const int* __restrict__ m_splits, const int* __restrict__ meta,
    float* __restrict__ out) {
  __shared__ char smem[2 * LDSBUF];   // 48 KiB

  // Arithmetic job mapping: jobs enumerated e-major, nt, then M-tile t;
  // contiguous jidx chunks per XCD (bid%8 -> XCD round-robin heuristic), so
  // same-(e,nt) jobs run consecutively on one XCD and share its L2 W-slice.
  const int J = meta[0];
  const int xcd = blockIdx.x & 7;
  const int pos = blockIdx.x >> 3;
  const int q = J >> 3, r = J & 7;
  if (pos >= q + (xcd < r ? 1 : 0)) return;           // padding block
  const int jidx = xcd * q + min(xcd, r) + pos;

  int lo = 0, hi = 64;                 // largest e with jb[e]*11 <= jidx
  while (hi - lo > 1) {
    const int mid = (lo + hi) >> 1;
    if (meta[1 + mid] * NTILE <= jidx) lo = mid; else hi = mid;
  }
  const int e = lo;
  const int mt_e = meta[1 + e + 1] - meta[1 + e];
  const int rem = jidx - meta[1 + e] * NTILE;
  const int nt = rem / mt_e;
  const int t  = rem - nt * mt_e;
  const int m_e = m_splits[e];
  const int row0 = meta[66 + e] + t * BM;
  const int nrows = min(BM, m_e - t * BM);
  const int n0 = nt * BN;

  const int tid  = threadIdx.x;
  const int lane = tid & 63;
  const int w    = tid >> 6;   // 8 waves
  const int wm   = w >> 1;     // 0..3 (64-row stripe of 256)
  const int wn   = w & 1;      // 0..1 (64-col stripe of 128)

  const int strow = tid >> 2;        // staging row 0..127
  const int skc8  = (tid & 3) * 8;   // k-offset (floats) of this thread's chunk
  const int kcb   = (tid & 3) * 16;  // byte offset within 64 B LDS row

  const float* xrow = x + (size_t)row0 * K_;
  const float* wrow = W + ((size_t)e * N_ + (size_t)n0) * K_;
  const f32x4 zero4 = {0.f, 0.f, 0.f, 0.f};

  auto load_tiles = [&](int kt, Stage& st) {
    const int kbase = kt * BK + skc8;
#pragma unroll
    for (int c = 0; c < 2; ++c) {
      const int rr = c * 128 + strow;
      if (rr < nrows) {
        const float* pp = xrow + (size_t)rr * K_ + kbase;
        st.a[c][0] = *(const f32x4*)pp;
        st.a[c][1] = *(const f32x4*)(pp + 4);
      } else { st.a[c][0] = zero4; st.a[c][1] = zero4; }
    }
    const float* qq = wrow + (size_t)strow * K_ + kbase;
    st.b[0] = *(const f32x4*)qq;
    st.b[1] = *(const f32x4*)(qq + 4);
  };

  // 64 B rows, 4x16B slots; slot ^= (r>>1)&3 -> frag reads conflict-free
  auto write_lds = [&](int buf, const Stage& st) {
    const int base = buf * LDSBUF;
#pragma unroll
    for (int c = 0; c < 2; ++c) {
      const int rr = c * 128 + strow;
      const int off = rr * 64 + (kcb ^ (((rr >> 1) & 3) << 4));
      bf16x8 v;
#pragma unroll
      for (int i = 0; i < 4; ++i) { v[i] = f2b(st.a[c][0][i]); v[i + 4] = f2b(st.a[c][1][i]); }
      *(bf16x8*)(smem + base + off) = v;
    }
    {
      const int rr = strow;
      const int off = rr * 64 + (kcb ^ (((rr >> 1) & 3) << 4));
      bf16x8 v;
#pragma unroll
      for (int i = 0; i < 4; ++i) { v[i] = f2b(st.b[0][i]); v[i + 4] = f2b(st.b[1][i]); }
      *(bf16x8*)(smem + base + LDSA + off) = v;
    }
  };

  f32x4 acc[4][4];
#pragma unroll
  for (int i = 0; i < 4; ++i)
#pragma unroll
    for (int j = 0; j < 4; ++j) acc[i][j] = zero4;

  const int arow0 = wm * 64 + (lane & 15);
  const int brow0 = wn * 64 + (lane & 15);
  const int kslot = (lane >> 4) * 16;

  auto compute = [&](int buf) {
    const int base = buf * LDSBUF;
    bf16x8 af[4], bfr[4];
#pragma unroll
    for (int i = 0; i < 4; ++i) {
      const int rr = arow0 + i * 16;
      af[i] = *(const bf16x8*)(smem + base + rr * 64 + (kslot ^ (((rr >> 1) & 3) << 4)));
    }
#pragma unroll
    for (int j = 0; j < 4; ++j) {
      const int rr = brow0 + j * 16;
      bfr[j] = *(const bf16x8*)(smem + base + LDSA + rr * 64 + (kslot ^ (((rr >> 1) & 3) << 4)));
    }
#pragma unroll
    for (int i = 0; i < 4; ++i)
#pragma unroll
      for (int j = 0; j < 4; ++j)
        acc[i][j] = __builtin_amdgcn_mfma_f32_16x16x32_bf16(af[i], bfr[j], acc[i][j], 0, 0, 0);
  };

  // 1-deep prefetch, double-buffered LDS, one lgkm-barrier per K-tile;
  // global loads stay in flight across barriers (vmcnt waited at write_lds,
  // which sits AFTER the MFMA cluster -> staging latency hidden by compute).
  Stage sA;
  load_tiles(0, sA);
  write_lds(0, sA);                // prologue-only exposed vmcnt
  int cur = 0;
  for (int kt = 0; kt < NK; ++kt) {
    if (kt + 1 < NK) load_tiles(kt + 1, sA);
    BAR();                                // publishes buf `cur`
    compute(cur);
    if (kt + 1 < NK) write_lds(cur ^ 1, sA);
    cur ^= 1;
  }

  // epilogue: C/D layout col=lane&15, row=(lane>>4)*4+reg
  const int crow = wm * 64 + (lane >> 4) * 4;
  const int ccol = n0 + wn * 64 + (lane & 15);
#pragma unroll
  for (int i = 0; i < 4; ++i) {
#pragma unroll
    for (int rr = 0; rr < 4; ++rr) {
      const int lr = crow + i * 16 + rr;
      if (lr < nrows) {
#pragma unroll
        for (int j = 0; j < 4; ++j)
          out[(size_t)(row0 + lr) * N_ + ccol + j * 16] = acc[i][j][rr];
      }
    }
  }
}

extern "C" void kernel_launch(void* const* d_in, const int* in_sizes, int n_in,
                              void* d_out, int out_size, void* d_ws, size_t ws_size,
                              hipStream_t stream) {
  const float* x        = (const float*)d_in[0];
  const float* W        = (const float*)d_in[1];
  const int*   m_splits = (const int*)d_in[2];
  float*       out      = (float*)d_out;

  int* meta = (int*)d_ws;   // 131 ints

  build_meta<<<1, 64, 0, stream>>>(m_splits, meta);
  gemm_grouped<<<GRID_, NTHREADS, 0, stream>>>(x, W, m_splits, meta, out);
}